// Round 7
// baseline (142.882 us; speedup 1.0000x reference)
//
#include <hip/hip_runtime.h>

#define B_DIMC   128
#define S_DIMC   4096
#define N_TOK    (B_DIMC * S_DIMC)
#define CHUNK    256                 // tokens per msc block == scan chunk
#define N_CHUNK  (N_TOK / CHUNK)     // 2048
#define CPB      (S_DIMC / CHUNK)    // 16 chunks per batch

typedef __attribute__((ext_vector_type(8))) short  short8;   // 8 bf16 (4 VGPR) MFMA A/B frag
typedef __attribute__((ext_vector_type(4))) float  floatx4;  // MFMA C/D frag
typedef __attribute__((ext_vector_type(4))) int    intx4;
typedef __attribute__((ext_vector_type(2))) int    intx2;

__device__ __forceinline__ unsigned short f2bf(float f) {
    unsigned u = __builtin_bit_cast(unsigned, f);
    u = (u + 0x7FFFu + ((u >> 16) & 1u)) >> 16;   // round-to-nearest-even
    return (unsigned short)u;
}
__device__ __forceinline__ int packbf(float a, float b) {
    return (int)f2bf(a) | ((int)f2bf(b) << 16);
}
// tanh(x) = 1 - 2/(exp2(2*log2e*x)+1); med3 clamp keeps exp2 in range
__device__ __forceinline__ float fast_tanh(float x) {
    float e = __builtin_amdgcn_exp2f(2.885390082f * __builtin_amdgcn_fmed3f(x, -9.0f, 9.0f));
    return fmaf(-2.0f, __builtin_amdgcn_rcpf(e + 1.0f), 1.0f);
}
// tanh(a)*tanh(b) = (t-u)/(t+u),  t = ea*eb+1, u = ea+eb,  e* = exp2(2log2e*x)
__device__ __forceinline__ float gate2(float a, float b) {
    const float c = 2.885390082f;
    float ea = __builtin_amdgcn_exp2f(c * __builtin_amdgcn_fmed3f(a, -9.0f, 9.0f));
    float eb = __builtin_amdgcn_exp2f(c * __builtin_amdgcn_fmed3f(b, -9.0f, 9.0f));
    float t  = fmaf(ea, eb, 1.0f);
    float u  = ea + eb;
    return (t - u) * __builtin_amdgcn_rcpf(t + u);
}

// head weight element for column n, contraction index k
__device__ __forceinline__ float head_w(int n, int k,
                                        const float* Wal, const float* Wbe,
                                        const float* Wga, const float* Wc) {
    if (n == 0) return Wal[k];
    if (n == 1) return Wbe[k];
    if (n == 2) return Wga[k];
    if (n < 8)  return Wc[k * 5 + (n - 3)];
    return 0.0f;
}

// LDS time-multiplex: weight-staging area (phase 1) is dead once fragments are
// in registers; A-activation zones (phase 2) reuse the same bytes. Rows padded
// to 40 shorts (80 B, 16B-multiple): b128 frag reads land 2-way max (free).
union SMemU {
    struct {
        short W[4][32][40];    // [a0,b0,a1,b1][outcol][k] bf16  (= W^T in MFMA-A layout)
        short Wh[16][40];      // head [outcol][k] bf16
    } b;
    short A[4][64][40];        // per-wave activations [tok][k] bf16 (later fp32 head rows)
};

// -------- single fused kernel: chunk-prefix + MFMA MLP (transposed form) --------
// All matmuls computed as C^T = W^T * G^T: weights are the MFMA A-operand,
// activations the B-operand. D[outcol=quad*4+r][token=lane&15] => for a fixed
// lane the 4 results are CONSECUTIVE k in one token row: 1 ds_write_b64 + 2
// packs replaces 4 scattered ds_write_b16 + 4 roundings per (mt,nt).
__global__ __launch_bounds__(256) void msc_kernel(
    const float* __restrict__ h_prev, const float* __restrict__ dx,
    const float* __restrict__ Wa0, const float* __restrict__ ba0,
    const float* __restrict__ Wb0, const float* __restrict__ bb0,
    const float* __restrict__ Wa1, const float* __restrict__ ba1,
    const float* __restrict__ Wb1, const float* __restrict__ bb1,
    const float* __restrict__ W_alpha, const float* __restrict__ b_alpha,
    const float* __restrict__ W_beta,  const float* __restrict__ b_beta,
    const float* __restrict__ W_gamma, const float* __restrict__ b_gamma,
    const float* __restrict__ W_c,     const float* __restrict__ b_c,
    const float* __restrict__ W_out,
    float* __restrict__ out)
{
    __shared__ __align__(16) SMemU sm;
    __shared__ __align__(16) float sTemps[4][64];   // per-wave temp_seq (fp32!)
    __shared__ __align__(16) float sHb[16];         // head bias (persistent)
    __shared__ float sWsum[4];                      // per-wave df2 totals
    __shared__ float sCred[4];                      // per-wave chunk-prefix partials

    const int tid  = threadIdx.x;
    const int w    = tid >> 6;
    const int lane = tid & 63;
    const int n    = lane & 15;
    const int quad = lane >> 4;
    const int t    = blockIdx.x * CHUNK + tid;

    // ---- per-token global loads ----
    const float* hp = h_prev + (size_t)t * 5;
    const float* d  = dx     + (size_t)t * 6;
    const float hp0 = hp[0], hp1 = hp[1], hp2 = hp[2], hp3 = hp[3], hp4 = hp[4];
    const float df0 = d[0], df1 = d[1], df2 = d[2];

    // ---- fused chunk prefix: sum dx2 over all preceding chunks of this batch ----
    // (replaces the old chunksum kernel + g_chunksums global round-trip)
    const int batch = blockIdx.x / CPB;
    const int cib   = blockIdx.x % CPB;
    {
        const float* dx2 = dx + (size_t)batch * S_DIMC * 6 + 2;
        float part = 0.0f;
        for (int c = 0; c < cib; ++c)            // uniform trip count, coalesced
            part += dx2[(size_t)(c * CHUNK + tid) * 6];
        #pragma unroll
        for (int m = 1; m < 64; m <<= 1) part += __shfl_xor(part, m, 64);
        if (lane == 0) sCred[w] = part;
    }

    // ---- wave-level inclusive scan of df2 ----
    float x = df2;
    #pragma unroll
    for (int off = 1; off < 64; off <<= 1) {
        float y = __shfl_up(x, off, 64);
        if (lane >= off) x += y;
    }
    if (lane == 63) sWsum[w] = x;

    // ---- phase 1: cooperative weight staging (bf16, [outcol][k], invalid k zeroed) ----
    #pragma unroll
    for (int m = 0; m < 4; ++m) {
        const float* Wsrc = (m == 0) ? Wa0 : (m == 1) ? Wb0 : (m == 2) ? Wa1 : Wb1;
        const bool l0 = (m < 2);
        #pragma unroll
        for (int dd = tid; dd < 512; dd += 256) {
            const int col = dd >> 4, kd = dd & 15, k0 = kd * 2, k1 = k0 + 1;
            float v0, v1;
            if (l0) {
                v0 = (k0 < 9 && k0 != 5) ? Wsrc[k0 * 32 + col] : 0.0f;
                v1 = (k1 < 9 && k1 != 5) ? Wsrc[k1 * 32 + col] : 0.0f;
            } else {
                v0 = Wsrc[k0 * 32 + col];
                v1 = Wsrc[k1 * 32 + col];
            }
            ((int*)&sm.b.W[m][col][0])[kd] = packbf(v0, v1);
        }
    }
    {   // head weights: 16 outcols x 32 k, one dword per thread
        const int hn = tid >> 4, kd = tid & 15, k0 = kd * 2;
        const float v0 = head_w(hn, k0,     W_alpha, W_beta, W_gamma, W_c);
        const float v1 = head_w(hn, k0 + 1, W_alpha, W_beta, W_gamma, W_c);
        ((int*)&sm.b.Wh[hn][0])[kd] = packbf(v0, v1);
    }
    if (tid < 16) {
        sHb[tid] = (tid == 0) ? b_alpha[0] : (tid == 1) ? b_beta[0]
                 : (tid == 2) ? b_gamma[0] : (tid < 8) ? b_c[tid - 3] : 0.0f;
    }

    __syncthreads();   // staging + sWsum + sCred visible

    // ---- weight fragments to registers (MFMA A-operand) ----
    short8 Wa0f[2], Wb0f[2], Wa1f[2], Wb1f[2], Whf;
    #pragma unroll
    for (int nt = 0; nt < 2; ++nt) {
        const int col = nt * 16 + n;
        Wa0f[nt] = *(const short8*)&sm.b.W[0][col][quad * 8];
        Wb0f[nt] = *(const short8*)&sm.b.W[1][col][quad * 8];
        Wa1f[nt] = *(const short8*)&sm.b.W[2][col][quad * 8];
        Wb1f[nt] = *(const short8*)&sm.b.W[3][col][quad * 8];
    }
    Whf = *(const short8*)&sm.b.Wh[n][quad * 8];

    // ---- temp_seq (fp32, stays out of bf16 path) ----
    const float coff = dx[(size_t)batch * S_DIMC * 6 + 5]      // init_temp
                     + sCred[0] + sCred[1] + sCred[2] + sCred[3];
    float pre = coff;
    if (w > 0) pre += sWsum[0];
    if (w > 1) pre += sWsum[1];
    if (w > 2) pre += sWsum[2];
    const float temp_t = pre + x;

    __syncthreads();   // all reads of sm.b done — safe to overwrite as sm.A

    sTemps[w][lane] = temp_t;

    // ---- phase 2: write input row L: [h(5), 0(temp folded to C), dir(3), 0...] ----
    const float nrm = fmaxf(sqrtf(df0*df0 + df1*df1 + df2*df2), 1e-7f);
    const float inv = __builtin_amdgcn_rcpf(nrm);
    {
        int* arow = (int*)&sm.A[w][lane][0];
        intx4 v0 = { packbf(hp0, hp1), packbf(hp2, hp3),
                     packbf(hp4, 0.0f), packbf(df0*inv, df1*inv) };
        intx4 v1 = { packbf(df2*inv, 0.0f), 0, 0, 0 };
        intx4 z  = { 0, 0, 0, 0 };
        *(intx4*)&arow[0]  = v0;
        *(intx4*)&arow[4]  = v1;
        *(intx4*)&arow[8]  = z;
        *(intx4*)&arow[12] = z;
    }

    // ---- layer-0 C-init constants: outcols nt*16+quad*4..+3 (float4, L1-hot) ----
    floatx4 w5a4[2], w5b4[2], bA04[2], bB04[2];
    #pragma unroll
    for (int nt = 0; nt < 2; ++nt) {
        const int col = nt * 16 + quad * 4;
        w5a4[nt] = *(const floatx4*)&Wa0[5 * 32 + col];
        w5b4[nt] = *(const floatx4*)&Wb0[5 * 32 + col];
        bA04[nt] = *(const floatx4*)&ba0[col];
        bB04[nt] = *(const floatx4*)&bb0[col];
    }

    // ---- layer 0: D[outcol][token] = W0^T * L^T;  C-init = bias + temp[token]*W5 ----
    #pragma unroll
    for (int mt = 0; mt < 4; ++mt) {
        const short8 Bf    = *(const short8*)&sm.A[w][mt * 16 + n][quad * 8];
        const float  tempn = sTemps[w][mt * 16 + n];
        #pragma unroll
        for (int nt = 0; nt < 2; ++nt) {
            floatx4 Ca, Cb;
            #pragma unroll
            for (int r = 0; r < 4; ++r) {
                Ca[r] = fmaf(tempn, w5a4[nt][r], bA04[nt][r]);
                Cb[r] = fmaf(tempn, w5b4[nt][r], bB04[nt][r]);
            }
            Ca = __builtin_amdgcn_mfma_f32_16x16x32_bf16(Wa0f[nt], Bf, Ca, 0, 0, 0);
            Cb = __builtin_amdgcn_mfma_f32_16x16x32_bf16(Wb0f[nt], Bf, Cb, 0, 0, 0);
            const int lo = packbf(gate2(Ca[0], Cb[0]), gate2(Ca[1], Cb[1]));
            const int hi = packbf(gate2(Ca[2], Cb[2]), gate2(Ca[3], Cb[3]));
            *(intx2*)&sm.A[w][mt * 16 + n][nt * 16 + quad * 4] = (intx2){ lo, hi };
        }
    }

    // ---- layer-1 bias constants ----
    floatx4 bA14[2], bB14[2];
    #pragma unroll
    for (int nt = 0; nt < 2; ++nt) {
        const int col = nt * 16 + quad * 4;
        bA14[nt] = *(const floatx4*)&ba1[col];
        bB14[nt] = *(const floatx4*)&bb1[col];
    }

    // ---- layer 1 ----
    #pragma unroll
    for (int mt = 0; mt < 4; ++mt) {
        const short8 Bf = *(const short8*)&sm.A[w][mt * 16 + n][quad * 8];
        #pragma unroll
        for (int nt = 0; nt < 2; ++nt) {
            floatx4 Ca = bA14[nt];
            floatx4 Cb = bB14[nt];
            Ca = __builtin_amdgcn_mfma_f32_16x16x32_bf16(Wa1f[nt], Bf, Ca, 0, 0, 0);
            Cb = __builtin_amdgcn_mfma_f32_16x16x32_bf16(Wb1f[nt], Bf, Cb, 0, 0, 0);
            const int lo = packbf(gate2(Ca[0], Cb[0]), gate2(Ca[1], Cb[1]));
            const int hi = packbf(gate2(Ca[2], Cb[2]), gate2(Ca[3], Cb[3]));
            *(intx2*)&sm.A[w][mt * 16 + n][nt * 16 + quad * 4] = (intx2){ lo, hi };
        }
    }

    // ---- heads: prefetch all G2 B-frags, then MFMA + fp32 store (quads 0-1) ----
    short8 Bh[4];
    #pragma unroll
    for (int mt = 0; mt < 4; ++mt)
        Bh[mt] = *(const short8*)&sm.A[w][mt * 16 + n][quad * 8];
    __syncthreads();   // ordering fence: short-typed reads above vs float stores below

    const floatx4 hbias4 = *(const floatx4*)&sHb[quad * 4];
    float* hc = (float*)&sm.A[w][0][0];   // [tok][12 dwords] fp32, fits in wave zone
    #pragma unroll
    for (int mt = 0; mt < 4; ++mt) {
        floatx4 C = hbias4;
        C = __builtin_amdgcn_mfma_f32_16x16x32_bf16(Whf, Bh[mt], C, 0, 0, 0);
        if (quad < 2)
            *(floatx4*)&hc[(mt * 16 + n) * 12 + quad * 4] = C;
    }

    const floatx4 h0v = *(const floatx4*)&hc[lane * 12];      // pa, pb, pg, pc0
    const floatx4 h1v = *(const floatx4*)&hc[lane * 12 + 4];  // pc1..pc4

    // ---- per-token epilogue ----
    const float alpha = __expf(h0v[0]);
    const float beta  = __expf(h0v[1]);
    const float gamma = __expf(h0v[2]);
    const float z     = 1.0f - __expf(-(alpha * fabsf(df0) + beta * df1 + gamma * fabsf(df2)));
    const float omz   = 1.0f - z;

    const float c0 = fast_tanh(h0v[3]), c1 = fast_tanh(h1v[0]), c2 = fast_tanh(h1v[1]),
                c3 = fast_tanh(h1v[2]), c4 = fast_tanh(h1v[3]);

    const float hn0 = omz * hp0 + z * c0;
    const float hn1 = omz * hp1 + z * c1;
    const float hn2 = omz * hp2 + z * c2;
    const float hn3 = omz * hp3 + z * c3;
    const float hn4 = omz * hp4 + z * c4;

    float* out_h = out + (size_t)t * 5;
    out_h[0] = hn0; out_h[1] = hn1; out_h[2] = hn2; out_h[3] = hn3; out_h[4] = hn4;
    out[(size_t)N_TOK * 5 + t] =
        hn0 * W_out[0] + hn1 * W_out[1] + hn2 * W_out[2] + hn3 * W_out[3] + hn4 * W_out[4];
}

extern "C" void kernel_launch(void* const* d_in, const int* in_sizes, int n_in,
                              void* d_out, int out_size, void* d_ws, size_t ws_size,
                              hipStream_t stream) {
    const float* h_prev  = (const float*)d_in[0];
    const float* dx      = (const float*)d_in[1];
    const float* Wa0     = (const float*)d_in[2];
    const float* ba0     = (const float*)d_in[3];
    const float* Wb0     = (const float*)d_in[4];
    const float* bb0     = (const float*)d_in[5];
    const float* Wa1     = (const float*)d_in[6];
    const float* ba1     = (const float*)d_in[7];
    const float* Wb1     = (const float*)d_in[8];
    const float* bb1     = (const float*)d_in[9];
    const float* W_alpha = (const float*)d_in[10];
    const float* b_alpha = (const float*)d_in[11];
    const float* W_beta  = (const float*)d_in[12];
    const float* b_beta  = (const float*)d_in[13];
    const float* W_gamma = (const float*)d_in[14];
    const float* b_gamma = (const float*)d_in[15];
    const float* W_c     = (const float*)d_in[16];
    const float* b_c     = (const float*)d_in[17];
    const float* W_out   = (const float*)d_in[18];
    float* out = (float*)d_out;

    msc_kernel<<<N_CHUNK, CHUNK, 0, stream>>>(
        h_prev, dx,
        Wa0, ba0, Wb0, bb0, Wa1, ba1, Wb1, bb1,
        W_alpha, b_alpha, W_beta, b_beta, W_gamma, b_gamma,
        W_c, b_c, W_out, out);
}

// Round 8
// 134.729 us; speedup vs baseline: 1.0605x; 1.0605x over previous
//
#include <hip/hip_runtime.h>

#define B_DIMC   128
#define S_DIMC   4096
#define N_TOK    (B_DIMC * S_DIMC)
#define CHUNK    256                 // tokens per msc block
#define N_BLK    (N_TOK / CHUNK)     // 2048
#define WCHUNK   64                  // scan chunk = one wave
#define N_WCH    (N_TOK / WCHUNK)    // 8192
#define WPB      (S_DIMC / WCHUNK)   // 64 wave-chunks per batch

typedef __attribute__((ext_vector_type(8))) short  short8;   // 8 bf16 (4 VGPR) MFMA A/B frag
typedef __attribute__((ext_vector_type(4))) float  floatx4;  // MFMA C/D frag
typedef __attribute__((ext_vector_type(4))) int    intx4;
typedef __attribute__((ext_vector_type(2))) int    intx2;

__device__ float g_chunksums[N_WCH];

__device__ __forceinline__ unsigned short f2bf(float f) {
    unsigned u = __builtin_bit_cast(unsigned, f);
    u = (u + 0x7FFFu + ((u >> 16) & 1u)) >> 16;   // round-to-nearest-even
    return (unsigned short)u;
}
__device__ __forceinline__ int packbf(float a, float b) {
    return (int)f2bf(a) | ((int)f2bf(b) << 16);
}
// tanh(x) = 1 - 2/(exp2(2*log2e*x)+1); med3 clamp keeps exp2 in range
__device__ __forceinline__ float fast_tanh(float x) {
    float e = __builtin_amdgcn_exp2f(2.885390082f * __builtin_amdgcn_fmed3f(x, -9.0f, 9.0f));
    return fmaf(-2.0f, __builtin_amdgcn_rcpf(e + 1.0f), 1.0f);
}
// tanh(a)*tanh(b) = (t-u)/(t+u),  t = ea*eb+1, u = ea+eb,  e* = exp2(2log2e*x)
__device__ __forceinline__ float gate2(float a, float b) {
    const float c = 2.885390082f;
    float ea = __builtin_amdgcn_exp2f(c * __builtin_amdgcn_fmed3f(a, -9.0f, 9.0f));
    float eb = __builtin_amdgcn_exp2f(c * __builtin_amdgcn_fmed3f(b, -9.0f, 9.0f));
    float t  = fmaf(ea, eb, 1.0f);
    float u  = ea + eb;
    return (t - u) * __builtin_amdgcn_rcpf(t + u);
}

// -------- K1: per-64-token-chunk sum of delta_x[..., 2] (wave-autonomous) --------
__global__ __launch_bounds__(256) void chunksum_kernel(const float* __restrict__ dx) {
    const int tid  = threadIdx.x;
    const int gc   = blockIdx.x * 4 + (tid >> 6);   // global 64-chunk id
    const int lane = tid & 63;
    float x = dx[((size_t)gc * WCHUNK + lane) * 6 + 2];
    #pragma unroll
    for (int off = 32; off >= 1; off >>= 1) x += __shfl_down(x, off, 64);
    if (lane == 0) g_chunksums[gc] = x;
}

// head weight element for column n, contraction index k
__device__ __forceinline__ float head_w(int n, int k,
                                        const float* Wal, const float* Wbe,
                                        const float* Wga, const float* Wc) {
    if (n == 0) return Wal[k];
    if (n == 1) return Wbe[k];
    if (n == 2) return Wga[k];
    if (n < 8)  return Wc[k * 5 + (n - 3)];
    return 0.0f;
}

// LDS time-multiplex: weight-staging area (phase 1) is dead once fragments are
// in registers; A-activation zones (phase 2) reuse the same bytes. Rows padded
// to 40 shorts (80 B, 16B-multiple): b128 frag reads land 2-way max (free).
union SMemU {
    struct {
        short W[4][32][40];    // [a0,b0,a1,b1][outcol][k] bf16  (= W^T in MFMA-A layout)
        short Wh[16][40];      // head [outcol][k] bf16
    } b;
    short A[4][64][40];        // per-wave activations [tok][k] bf16 (later fp32 head rows)
};

// -------- K2: MFMA token-parallel MLP, wave-autonomous after staging --------
// Transposed form: C^T = W^T * G^T (weights = MFMA A-operand). D[outcol=quad*4+r]
// [token=lane&15] => 4 gate results are consecutive k in one token row:
// 1 ds_write_b64 + 2 packs per (mt,nt). After the two staging barriers there is
// NO cross-wave data flow: scan prefix comes from g_chunksums per wave.
__global__ __launch_bounds__(256) void msc_kernel(
    const float* __restrict__ h_prev, const float* __restrict__ dx,
    const float* __restrict__ Wa0, const float* __restrict__ ba0,
    const float* __restrict__ Wb0, const float* __restrict__ bb0,
    const float* __restrict__ Wa1, const float* __restrict__ ba1,
    const float* __restrict__ Wb1, const float* __restrict__ bb1,
    const float* __restrict__ W_alpha, const float* __restrict__ b_alpha,
    const float* __restrict__ W_beta,  const float* __restrict__ b_beta,
    const float* __restrict__ W_gamma, const float* __restrict__ b_gamma,
    const float* __restrict__ W_c,     const float* __restrict__ b_c,
    const float* __restrict__ W_out,
    float* __restrict__ out)
{
    __shared__ __align__(16) SMemU sm;
    __shared__ __align__(16) float sTemps[4][64];   // per-wave temp_seq (fp32!)
    __shared__ __align__(16) float sHb[16];         // head bias (persistent)

    const int tid  = threadIdx.x;
    const int w    = tid >> 6;
    const int lane = tid & 63;
    const int n    = lane & 15;
    const int quad = lane >> 4;
    const int t    = blockIdx.x * CHUNK + tid;

    // ---- per-token global loads ----
    const float* hp = h_prev + (size_t)t * 5;
    const float* d  = dx     + (size_t)t * 6;
    const float hp0 = hp[0], hp1 = hp[1], hp2 = hp[2], hp3 = hp[3], hp4 = hp[4];
    const float df0 = d[0], df1 = d[1], df2 = d[2];

    // ---- per-wave chunk prefix: 1 coalesced load/lane + butterfly ----
    const int gw    = blockIdx.x * 4 + w;    // global 64-chunk id == wave id
    const int batch = gw / WPB;
    const int cib   = gw % WPB;              // 0..63 preceding chunks
    float cs = (lane < cib) ? g_chunksums[batch * WPB + lane] : 0.0f;
    #pragma unroll
    for (int m = 1; m < 64; m <<= 1) cs += __shfl_xor(cs, m, 64);
    const float coff = dx[(size_t)batch * S_DIMC * 6 + 5] + cs;   // init_temp + prefix

    // ---- wave-level inclusive scan of df2 ----
    float x = df2;
    #pragma unroll
    for (int off = 1; off < 64; off <<= 1) {
        float y = __shfl_up(x, off, 64);
        if (lane >= off) x += y;
    }
    const float temp_t = coff + x;           // full temp_seq value, fp32

    // ---- phase 1: cooperative weight staging (bf16, [outcol][k], invalid k zeroed) ----
    #pragma unroll
    for (int m = 0; m < 4; ++m) {
        const float* Wsrc = (m == 0) ? Wa0 : (m == 1) ? Wb0 : (m == 2) ? Wa1 : Wb1;
        const bool l0 = (m < 2);
        #pragma unroll
        for (int dd = tid; dd < 512; dd += 256) {
            const int col = dd >> 4, kd = dd & 15, k0 = kd * 2, k1 = k0 + 1;
            float v0, v1;
            if (l0) {
                v0 = (k0 < 9 && k0 != 5) ? Wsrc[k0 * 32 + col] : 0.0f;
                v1 = (k1 < 9 && k1 != 5) ? Wsrc[k1 * 32 + col] : 0.0f;
            } else {
                v0 = Wsrc[k0 * 32 + col];
                v1 = Wsrc[k1 * 32 + col];
            }
            ((int*)&sm.b.W[m][col][0])[kd] = packbf(v0, v1);
        }
    }
    {   // head weights: 16 outcols x 32 k, one dword per thread
        const int hn = tid >> 4, kd = tid & 15, k0 = kd * 2;
        const float v0 = head_w(hn, k0,     W_alpha, W_beta, W_gamma, W_c);
        const float v1 = head_w(hn, k0 + 1, W_alpha, W_beta, W_gamma, W_c);
        ((int*)&sm.b.Wh[hn][0])[kd] = packbf(v0, v1);
    }
    if (tid < 16) {
        sHb[tid] = (tid == 0) ? b_alpha[0] : (tid == 1) ? b_beta[0]
                 : (tid == 2) ? b_gamma[0] : (tid < 8) ? b_c[tid - 3] : 0.0f;
    }

    __syncthreads();   // staging visible to all waves

    // ---- weight fragments to registers (MFMA A-operand) ----
    short8 Wa0f[2], Wb0f[2], Wa1f[2], Wb1f[2], Whf;
    #pragma unroll
    for (int nt = 0; nt < 2; ++nt) {
        const int col = nt * 16 + n;
        Wa0f[nt] = *(const short8*)&sm.b.W[0][col][quad * 8];
        Wb0f[nt] = *(const short8*)&sm.b.W[1][col][quad * 8];
        Wa1f[nt] = *(const short8*)&sm.b.W[2][col][quad * 8];
        Wb1f[nt] = *(const short8*)&sm.b.W[3][col][quad * 8];
    }
    Whf = *(const short8*)&sm.b.Wh[n][quad * 8];

    __syncthreads();   // all reads of sm.b done — safe to overwrite as sm.A
                       // (last barrier: everything below is wave-private)

    sTemps[w][lane] = temp_t;

    // ---- phase 2: write input row L: [h(5), 0(temp folded to C), dir(3), 0...] ----
    const float nrm = fmaxf(sqrtf(df0*df0 + df1*df1 + df2*df2), 1e-7f);
    const float inv = __builtin_amdgcn_rcpf(nrm);
    {
        int* arow = (int*)&sm.A[w][lane][0];
        intx4 v0 = { packbf(hp0, hp1), packbf(hp2, hp3),
                     packbf(hp4, 0.0f), packbf(df0*inv, df1*inv) };
        intx4 v1 = { packbf(df2*inv, 0.0f), 0, 0, 0 };
        intx4 z  = { 0, 0, 0, 0 };
        *(intx4*)&arow[0]  = v0;
        *(intx4*)&arow[4]  = v1;
        *(intx4*)&arow[8]  = z;
        *(intx4*)&arow[12] = z;
    }

    // ---- layer-0 C-init constants: outcols nt*16+quad*4..+3 (float4, L1-hot) ----
    floatx4 w5a4[2], w5b4[2], bA04[2], bB04[2];
    #pragma unroll
    for (int nt = 0; nt < 2; ++nt) {
        const int col = nt * 16 + quad * 4;
        w5a4[nt] = *(const floatx4*)&Wa0[5 * 32 + col];
        w5b4[nt] = *(const floatx4*)&Wb0[5 * 32 + col];
        bA04[nt] = *(const floatx4*)&ba0[col];
        bB04[nt] = *(const floatx4*)&bb0[col];
    }

    // ---- layer 0: D[outcol][token] = W0^T * L^T;  C-init = bias + temp[token]*W5 ----
    #pragma unroll
    for (int mt = 0; mt < 4; ++mt) {
        const short8 Bf    = *(const short8*)&sm.A[w][mt * 16 + n][quad * 8];
        const float  tempn = sTemps[w][mt * 16 + n];
        #pragma unroll
        for (int nt = 0; nt < 2; ++nt) {
            floatx4 Ca, Cb;
            #pragma unroll
            for (int r = 0; r < 4; ++r) {
                Ca[r] = fmaf(tempn, w5a4[nt][r], bA04[nt][r]);
                Cb[r] = fmaf(tempn, w5b4[nt][r], bB04[nt][r]);
            }
            Ca = __builtin_amdgcn_mfma_f32_16x16x32_bf16(Wa0f[nt], Bf, Ca, 0, 0, 0);
            Cb = __builtin_amdgcn_mfma_f32_16x16x32_bf16(Wb0f[nt], Bf, Cb, 0, 0, 0);
            const int lo = packbf(gate2(Ca[0], Cb[0]), gate2(Ca[1], Cb[1]));
            const int hi = packbf(gate2(Ca[2], Cb[2]), gate2(Ca[3], Cb[3]));
            *(intx2*)&sm.A[w][mt * 16 + n][nt * 16 + quad * 4] = (intx2){ lo, hi };
        }
    }

    // ---- layer-1 bias constants ----
    floatx4 bA14[2], bB14[2];
    #pragma unroll
    for (int nt = 0; nt < 2; ++nt) {
        const int col = nt * 16 + quad * 4;
        bA14[nt] = *(const floatx4*)&ba1[col];
        bB14[nt] = *(const floatx4*)&bb1[col];
    }

    // ---- layer 1 ----
    #pragma unroll
    for (int mt = 0; mt < 4; ++mt) {
        const short8 Bf = *(const short8*)&sm.A[w][mt * 16 + n][quad * 8];
        #pragma unroll
        for (int nt = 0; nt < 2; ++nt) {
            floatx4 Ca = bA14[nt];
            floatx4 Cb = bB14[nt];
            Ca = __builtin_amdgcn_mfma_f32_16x16x32_bf16(Wa1f[nt], Bf, Ca, 0, 0, 0);
            Cb = __builtin_amdgcn_mfma_f32_16x16x32_bf16(Wb1f[nt], Bf, Cb, 0, 0, 0);
            const int lo = packbf(gate2(Ca[0], Cb[0]), gate2(Ca[1], Cb[1]));
            const int hi = packbf(gate2(Ca[2], Cb[2]), gate2(Ca[3], Cb[3]));
            *(intx2*)&sm.A[w][mt * 16 + n][nt * 16 + quad * 4] = (intx2){ lo, hi };
        }
    }

    // ---- heads: prefetch all G2 B-frags (wave-private zone) ----
    short8 Bh[4];
    #pragma unroll
    for (int mt = 0; mt < 4; ++mt)
        Bh[mt] = *(const short8*)&sm.A[w][mt * 16 + n][quad * 8];
    // Per-wave fence (replaces __syncthreads): drain own ds_reads before the
    // fp32 stores below overwrite the same bytes; block compiler reordering.
    asm volatile("s_waitcnt lgkmcnt(0)" ::: "memory");

    const floatx4 hbias4 = *(const floatx4*)&sHb[quad * 4];
    float* hc = (float*)&sm.A[w][0][0];   // [tok][12 dwords] fp32, fits in wave zone
    #pragma unroll
    for (int mt = 0; mt < 4; ++mt) {
        floatx4 C = hbias4;
        C = __builtin_amdgcn_mfma_f32_16x16x32_bf16(Whf, Bh[mt], C, 0, 0, 0);
        if (quad < 2)
            *(floatx4*)&hc[(mt * 16 + n) * 12 + quad * 4] = C;
    }

    const floatx4 h0v = *(const floatx4*)&hc[lane * 12];      // pa, pb, pg, pc0
    const floatx4 h1v = *(const floatx4*)&hc[lane * 12 + 4];  // pc1..pc4

    // ---- per-token epilogue ----
    const float alpha = __expf(h0v[0]);
    const float beta  = __expf(h0v[1]);
    const float gamma = __expf(h0v[2]);
    const float z     = 1.0f - __expf(-(alpha * fabsf(df0) + beta * df1 + gamma * fabsf(df2)));
    const float omz   = 1.0f - z;

    const float c0 = fast_tanh(h0v[3]), c1 = fast_tanh(h1v[0]), c2 = fast_tanh(h1v[1]),
                c3 = fast_tanh(h1v[2]), c4 = fast_tanh(h1v[3]);

    const float hn0 = omz * hp0 + z * c0;
    const float hn1 = omz * hp1 + z * c1;
    const float hn2 = omz * hp2 + z * c2;
    const float hn3 = omz * hp3 + z * c3;
    const float hn4 = omz * hp4 + z * c4;

    float* out_h = out + (size_t)t * 5;
    out_h[0] = hn0; out_h[1] = hn1; out_h[2] = hn2; out_h[3] = hn3; out_h[4] = hn4;
    out[(size_t)N_TOK * 5 + t] =
        hn0 * W_out[0] + hn1 * W_out[1] + hn2 * W_out[2] + hn3 * W_out[3] + hn4 * W_out[4];
}

extern "C" void kernel_launch(void* const* d_in, const int* in_sizes, int n_in,
                              void* d_out, int out_size, void* d_ws, size_t ws_size,
                              hipStream_t stream) {
    const float* h_prev  = (const float*)d_in[0];
    const float* dx      = (const float*)d_in[1];
    const float* Wa0     = (const float*)d_in[2];
    const float* ba0     = (const float*)d_in[3];
    const float* Wb0     = (const float*)d_in[4];
    const float* bb0     = (const float*)d_in[5];
    const float* Wa1     = (const float*)d_in[6];
    const float* ba1     = (const float*)d_in[7];
    const float* Wb1     = (const float*)d_in[8];
    const float* bb1     = (const float*)d_in[9];
    const float* W_alpha = (const float*)d_in[10];
    const float* b_alpha = (const float*)d_in[11];
    const float* W_beta  = (const float*)d_in[12];
    const float* b_beta  = (const float*)d_in[13];
    const float* W_gamma = (const float*)d_in[14];
    const float* b_gamma = (const float*)d_in[15];
    const float* W_c     = (const float*)d_in[16];
    const float* b_c     = (const float*)d_in[17];
    const float* W_out   = (const float*)d_in[18];
    float* out = (float*)d_out;

    chunksum_kernel<<<N_WCH / 4, 256, 0, stream>>>(dx);
    msc_kernel<<<N_BLK, CHUNK, 0, stream>>>(
        h_prev, dx,
        Wa0, ba0, Wb0, bb0, Wa1, ba1, Wb1, bb1,
        W_alpha, b_alpha, W_beta, b_beta, W_gamma, b_gamma,
        W_c, b_c, W_out, out);
}